// Round 10
// baseline (185.848 us; speedup 1.0000x reference)
//
#include <hip/hip_runtime.h>

// B=4, H=W=64, N=4096, C=512, HEAD=8, dh=64, SR=4, Nk=256
// Split-bf16: val = hi + lo (both bf16). 3-term product drops only lo*lo (~4e-6 rel).

typedef __bf16 bf16x8 __attribute__((ext_vector_type(8)));
typedef float f32x4 __attribute__((ext_vector_type(4)));

__device__ __forceinline__ ushort f2bf(float v) {
  uint u = __float_as_uint(v);
  return (ushort)((u + 0x7FFFu + ((u >> 16) & 1u)) >> 16);
}
__device__ __forceinline__ float bf2f(ushort h) {
  return __uint_as_float((uint)h << 16);
}
__device__ __forceinline__ void gload16(const void* g, void* l) {
  __builtin_amdgcn_global_load_lds(
      (const __attribute__((address_space(1))) void*)g,
      (__attribute__((address_space(3))) void*)l, 16, 0, 0);
}
// bijective XCD swizzle for nwg % 8 == 0
__device__ __forceinline__ int xcd_swz(int bid, int nwg) {
  int cpx = nwg >> 3;
  return (bid & 7) * cpx + (bid >> 3);
}

// ---------------- fused prep: convert x, W's, Wsr, biases ----------------
__global__ __launch_bounds__(256) void prep_kernel(
    const float* __restrict__ x, const float* __restrict__ Wq,
    const float* __restrict__ Wp, const float* __restrict__ Wk,
    const float* __restrict__ Wv, const float* __restrict__ Wsr,
    const float* __restrict__ bk, const float* __restrict__ bv,
    ushort* __restrict__ xq, ushort* __restrict__ Wq_,
    ushort* __restrict__ Wp_, ushort* __restrict__ Wkv_,
    ushort* __restrict__ Wsr_, float* __restrict__ bkv) {
  __shared__ float t[32][33];
  int bid = blockIdx.x, tid = threadIdx.x;
  if (bid < 4096 + 512) {
    const float* src;
    ushort* dst;
    int gid;
    if (bid < 4096) {
      src = x; dst = xq; gid = bid * 256 + tid;
    } else {
      int z = (bid - 4096) >> 7;
      src = (z == 0) ? Wq : (z == 1) ? Wp : (z == 2) ? Wk : Wv;
      dst = (z == 0) ? Wq_ : (z == 1) ? Wp_ : (z == 2) ? Wkv_ : (Wkv_ + 512 * 1024);
      gid = ((bid - 4096) & 127) * 256 + tid;
    }
    int row = gid >> 6, c8 = (gid & 63) << 3;
    float4 a = *(const float4*)(src + (size_t)row * 512 + c8);
    float4 b = *(const float4*)(src + (size_t)row * 512 + c8 + 4);
    ushort h[8], l[8];
    float vv[8] = {a.x, a.y, a.z, a.w, b.x, b.y, b.z, b.w};
#pragma unroll
    for (int e = 0; e < 8; ++e) { h[e] = f2bf(vv[e]); l[e] = f2bf(vv[e] - bf2f(h[e])); }
    uint4 hp, lp;
    hp.x = h[0] | ((uint)h[1] << 16); hp.y = h[2] | ((uint)h[3] << 16);
    hp.z = h[4] | ((uint)h[5] << 16); hp.w = h[6] | ((uint)h[7] << 16);
    lp.x = l[0] | ((uint)l[1] << 16); lp.y = l[2] | ((uint)l[3] << 16);
    lp.z = l[4] | ((uint)l[5] << 16); lp.w = l[6] | ((uint)l[7] << 16);
    *(uint4*)(dst + (size_t)row * 1024 + c8) = hp;
    *(uint4*)(dst + (size_t)row * 1024 + 512 + c8) = lp;
  } else if (bid < 4096 + 512 + 4096) {
    int tb = bid - 4608;
    int z = tb >> 8, rem = tb & 255;
    int ci0 = (rem >> 4) << 5, co0 = (rem & 15) << 5;
    int tx = tid & 31, ty = tid >> 5;
#pragma unroll
    for (int i = 0; i < 32; i += 8)
      t[ty + i][tx] = Wsr[((size_t)z * 512 + ci0 + ty + i) * 512 + co0 + tx];
    __syncthreads();
#pragma unroll
    for (int i = 0; i < 32; i += 8) {
      float v = t[tx][ty + i];
      int co = co0 + ty + i, ci = ci0 + tx;
      ushort h = f2bf(v), l = f2bf(v - bf2f(h));
      Wsr_[((size_t)z * 512 + co) * 1024 + ci] = h;
      Wsr_[((size_t)z * 512 + co) * 1024 + 512 + ci] = l;
    }
  } else {
    bkv[tid] = bk[tid]; bkv[tid + 256] = bk[tid + 256];
    bkv[tid + 512] = bv[tid]; bkv[tid + 768] = bv[tid + 256];
  }
}

// ---------------- MFMA GEMM body: double-buffered 2-phase K-loop ----------------
// EPI=0: C fp32 + bias. EPI=1: Qsplit layout (LDS-coalesced). EPI=2: Kq/Vt scatter.
template <int EPI>
__device__ __forceinline__ void gemm_body(
    const ushort* __restrict__ A, const ushort* __restrict__ Bw,
    const float* __restrict__ bias, float* __restrict__ C,
    ushort* __restrict__ Qs, ushort* __restrict__ Kq, ushort* __restrict__ Vt,
    int N, int bx, int by, ushort* lds) {
  int tid = threadIdx.x;
  int lane = tid & 63, w = tid >> 6;
  int wr = w >> 1, wc = w & 1;
  int l15 = lane & 15, g = lane >> 4;
  int srow = lane >> 3;
  int scol = (lane & 7) ^ srow;

  const ushort* aBase = A + (size_t)(by * 128 + w * 32 + srow) * 1024 + scol * 8;
  const ushort* bBase = Bw + (size_t)(bx * 128 + w * 32 + srow) * 1024 + scol * 8;

  f32x4 acc[4][4];
#pragma unroll
  for (int i = 0; i < 4; ++i)
#pragma unroll
    for (int j = 0; j < 4; ++j) acc[i][j] = (f32x4){0.f, 0.f, 0.f, 0.f};

#define STAGE_G(ks, buf)                                              \
  {                                                                   \
    int kk = (ks) * 64;                                               \
    int ap = kk - (kk >= 1024 ? 1024 : 0);                            \
    int bp = kk - (kk >= 512 ? 512 : 0);                              \
    ushort* aD = lds + (buf) * 16384 + w * 2048;                      \
    ushort* bD = lds + (buf) * 16384 + 8192 + w * 2048;               \
    _Pragma("unroll") for (int t = 0; t < 4; ++t) {                   \
      gload16(aBase + (size_t)t * 8192 + ap, aD + t * 512);           \
      gload16(bBase + (size_t)t * 8192 + bp, bD + t * 512);           \
    }                                                                 \
  }

#define COMPUTE_G(buf)                                                         \
  {                                                                            \
    const ushort* As = lds + (buf) * 16384;                                    \
    const ushort* Bs = As + 8192;                                              \
    _Pragma("unroll") for (int kk2 = 0; kk2 < 2; ++kk2) {                      \
      int rb = kk2 * 4 + g;                                                    \
      bf16x8 af[4], bg[4];                                                     \
      _Pragma("unroll") for (int i = 0; i < 4; ++i) {                          \
        int row = wr * 64 + i * 16 + l15;                                      \
        af[i] = *(const bf16x8*)&As[row * 64 + ((rb ^ (row & 7)) << 3)];       \
      }                                                                        \
      _Pragma("unroll") for (int j = 0; j < 4; ++j) {                          \
        int col = wc * 64 + j * 16 + l15;                                      \
        bg[j] = *(const bf16x8*)&Bs[col * 64 + ((rb ^ (col & 7)) << 3)];       \
      }                                                                        \
      _Pragma("unroll") for (int i = 0; i < 4; ++i)                            \
        _Pragma("unroll") for (int j = 0; j < 4; ++j)                          \
          acc[i][j] =                                                          \
              __builtin_amdgcn_mfma_f32_16x16x32_bf16(af[i], bg[j], acc[i][j], \
                                                      0, 0, 0);                \
    }                                                                          \
  }

  STAGE_G(0, 0);
  __syncthreads();
  for (int ks = 0; ks < 23; ++ks) {
    STAGE_G(ks + 1, (ks + 1) & 1);
    COMPUTE_G(ks & 1);
    __syncthreads();
  }
  COMPUTE_G(1);

#undef STAGE_G
#undef COMPUTE_G

  if (EPI == 0) {
#pragma unroll
    for (int j = 0; j < 4; ++j) {
      int col = bx * 128 + wc * 64 + j * 16 + l15;
      float bj = bias ? bias[col] : 0.f;
#pragma unroll
      for (int i = 0; i < 4; ++i) {
        int row0 = by * 128 + wr * 64 + i * 16 + g * 4;
#pragma unroll
        for (int r = 0; r < 4; ++r)
          C[(size_t)(row0 + r) * N + col] = acc[i][j][r] + bj;
      }
    }
  } else if (EPI == 1) {
    __syncthreads();
#pragma unroll
    for (int j = 0; j < 4; ++j) {
      int cl = wc * 64 + j * 16 + l15;
      float bj = bias[bx * 128 + cl];
#pragma unroll
      for (int i = 0; i < 4; ++i) {
        int rl0 = wr * 64 + i * 16 + g * 4;
#pragma unroll
        for (int r = 0; r < 4; ++r) {
          float v = (acc[i][j][r] + bj) * 0.125f;
          ushort h = f2bf(v), lo = f2bf(v - bf2f(h));
          lds[(rl0 + r) * 128 + cl] = h;
          lds[16384 + (rl0 + r) * 128 + cl] = lo;
        }
      }
    }
    __syncthreads();
#pragma unroll
    for (int it = 0; it < 8; ++it) {
      int c = tid + it * 256;
      int r = c >> 4, ck = c & 15;
      int grow = by * 128 + r;
      size_t base = ((size_t)grow * 8 + bx * 2 + (ck >> 3)) * 128 + (ck & 7) * 8;
      *(uint4*)(Qs + base) = *(const uint4*)&lds[r * 128 + ck * 8];
      *(uint4*)(Qs + base + 64) = *(const uint4*)&lds[16384 + r * 128 + ck * 8];
    }
  } else {
    // EPI=2: kv epilogue — scatter split-bf16 directly into Kq / Vt layouts.
#pragma unroll
    for (int j = 0; j < 4; ++j) {
      int col = bx * 128 + wc * 64 + j * 16 + l15;
      float bj = bias[col];
      bool isK = col < 512;
      int cp = isK ? col : col - 512;
      int hh = cp >> 6, d = cp & 63;
#pragma unroll
      for (int i = 0; i < 4; ++i) {
        int row0 = by * 128 + wr * 64 + i * 16 + g * 4;
#pragma unroll
        for (int r = 0; r < 4; ++r) {
          int row = row0 + r;
          int b = row >> 8, kk = row & 255;
          float v = acc[i][j][r] + bj;
          ushort h = f2bf(v), lo = f2bf(v - bf2f(h));
          if (isK) {
            size_t base = ((size_t)((b * 8 + hh) * 256) + kk) * 128 + d;
            Kq[base] = h; Kq[base + 64] = lo;
          } else {
            size_t base = ((size_t)((b * 8 + hh) * 64) + d) * 512 + kk;
            Vt[base] = h; Vt[base + 256] = lo;
          }
        }
      }
    }
  }
}

// ---------------- conv body (split-16, one tap per z) ----------------
__device__ __forceinline__ void conv_body(
    const ushort* __restrict__ xq, const ushort* __restrict__ Wsr_,
    float* __restrict__ part, int bx, int by, int z, ushort* lds) {
  int kh = z >> 2, kw = z & 3;
  int tid = threadIdx.x;
  int lane = tid & 63, w = tid >> 6;
  int wr = w >> 1, wc = w & 1;
  int l15 = lane & 15, g = lane >> 4;
  int srow = lane >> 3;
  int scol = (lane & 7) ^ srow;

  const ushort* aBase[4];
#pragma unroll
  for (int t = 0; t < 4; ++t) {
    int gm = by * 128 + w * 32 + t * 8 + srow;
    int xr = (gm >> 8) * 4096 + ((((gm >> 4) & 15) << 2) + kh) * 64 +
             ((gm & 15) << 2) + kw;
    aBase[t] = xq + (size_t)xr * 1024 + scol * 8;
  }
  const ushort* bBase =
      Wsr_ + ((size_t)z * 512 + bx * 128 + w * 32 + srow) * 1024 + scol * 8;

  f32x4 acc[4][4];
#pragma unroll
  for (int i = 0; i < 4; ++i)
#pragma unroll
    for (int j = 0; j < 4; ++j) acc[i][j] = (f32x4){0.f, 0.f, 0.f, 0.f};

#define STAGE_C(ks, buf)                                              \
  {                                                                   \
    int kk = (ks) * 64;                                               \
    int ap = kk - (kk >= 1024 ? 1024 : 0);                            \
    int bp = kk - (kk >= 512 ? 512 : 0);                              \
    ushort* aD = lds + (buf) * 16384 + w * 2048;                      \
    ushort* bD = lds + (buf) * 16384 + 8192 + w * 2048;               \
    _Pragma("unroll") for (int t = 0; t < 4; ++t) {                   \
      gload16(aBase[t] + ap, aD + t * 512);                           \
      gload16(bBase + (size_t)t * 8192 + bp, bD + t * 512);           \
    }                                                                 \
  }

#define COMPUTE_C(buf)                                                         \
  {                                                                            \
    const ushort* As = lds + (buf) * 16384;                                    \
    const ushort* Bs = As + 8192;                                              \
    _Pragma("unroll") for (int kk2 = 0; kk2 < 2; ++kk2) {                      \
      int rb = kk2 * 4 + g;                                                    \
      bf16x8 af[4], bg[4];                                                     \
      _Pragma("unroll") for (int i = 0; i < 4; ++i) {                          \
        int row = wr * 64 + i * 16 + l15;                                      \
        af[i] = *(const bf16x8*)&As[row * 64 + ((rb ^ (row & 7)) << 3)];       \
      }                                                                        \
      _Pragma("unroll") for (int j = 0; j < 4; ++j) {                          \
        int col = wc * 64 + j * 16 + l15;                                      \
        bg[j] = *(const bf16x8*)&Bs[col * 64 + ((rb ^ (col & 7)) << 3)];       \
      }                                                                        \
      _Pragma("unroll") for (int i = 0; i < 4; ++i)                            \
        _Pragma("unroll") for (int j = 0; j < 4; ++j)                          \
          acc[i][j] =                                                          \
              __builtin_amdgcn_mfma_f32_16x16x32_bf16(af[i], bg[j], acc[i][j], \
                                                      0, 0, 0);                \
    }                                                                          \
  }

  STAGE_C(0, 0);
  __syncthreads();
  for (int ks = 0; ks < 23; ++ks) {
    STAGE_C(ks + 1, (ks + 1) & 1);
    COMPUTE_C(ks & 1);
    __syncthreads();
  }
  COMPUTE_C(1);

#undef STAGE_C
#undef COMPUTE_C

  float* Cp = part + (size_t)z * 524288;
#pragma unroll
  for (int j = 0; j < 4; ++j) {
    int col = bx * 128 + wc * 64 + j * 16 + l15;
#pragma unroll
    for (int i = 0; i < 4; ++i) {
      int row0 = by * 128 + wr * 64 + i * 16 + g * 4;
#pragma unroll
      for (int r = 0; r < 4; ++r)
        Cp[(size_t)(row0 + r) * 512 + col] = acc[i][j][r];
    }
  }
}

// conv (work-ids 0..511) + q-proj (512..1023); `base` lets the compact-ws path
// launch the halves separately (conv first, q-proj after ln).
__global__ __launch_bounds__(256) void cq_kernel(
    const ushort* __restrict__ xq, const ushort* __restrict__ Wsr_,
    float* __restrict__ part, const ushort* __restrict__ Wq_,
    const float* __restrict__ bq, ushort* __restrict__ Qs, int base) {
  __shared__ __align__(16) ushort lds[32768];
  int bid = xcd_swz(blockIdx.x, gridDim.x) + base;
  if (bid < 512) {
    conv_body(xq, Wsr_, part, bid & 3, (bid >> 2) & 7, bid >> 5, lds);
  } else {
    int b2 = bid - 512;
    gemm_body<1>(xq, Wq_, bq, nullptr, Qs, nullptr, nullptr, 512, b2 & 3, b2 >> 2, lds);
  }
}

// kv-proj: 64 blocks, writes Kq/Vt directly (EPI=2)
__global__ __launch_bounds__(256) void kvproj_kernel(
    const ushort* __restrict__ xkv_, const ushort* __restrict__ Wkv_,
    const float* __restrict__ bkv, ushort* __restrict__ Kq,
    ushort* __restrict__ Vt) {
  __shared__ __align__(16) ushort lds[32768];
  int bid = xcd_swz(blockIdx.x, 64);
  gemm_body<2>(xkv_, Wkv_, bkv, nullptr, nullptr, Kq, Vt, 1024, bid & 7, bid >> 3, lds);
}

// out-proj
__global__ __launch_bounds__(256) void gemm_out_kernel(
    const ushort* __restrict__ A, const ushort* __restrict__ Bw,
    const float* __restrict__ bias, float* __restrict__ C) {
  __shared__ __align__(16) ushort lds[32768];
  int bid = xcd_swz(blockIdx.x, 512);
  gemm_body<0>(A, Bw, bias, C, nullptr, nullptr, nullptr, 512, bid & 3, bid >> 2, lds);
}

// ---------------- partial-sum(16) + bias + LayerNorm -> split-bf16 ----------------
__global__ __launch_bounds__(256) void ln_kernel(
    const float* __restrict__ part, const float* __restrict__ bsr,
    const float* __restrict__ gamma, const float* __restrict__ beta,
    ushort* __restrict__ xkv_) {
  int row = blockIdx.x;
  int t = threadIdx.x;
  float v0 = bsr[t], v1 = bsr[t + 256];
  for (int p = 0; p < 16; ++p) {
    v0 += part[(size_t)p * 524288 + (size_t)row * 512 + t];
    v1 += part[(size_t)p * 524288 + (size_t)row * 512 + t + 256];
  }
  float s = v0 + v1, sq = v0 * v0 + v1 * v1;
#pragma unroll
  for (int o = 1; o < 64; o <<= 1) {
    s += __shfl_xor(s, o);
    sq += __shfl_xor(sq, o);
  }
  __shared__ float red[8];
  int wv = t >> 6;
  if ((t & 63) == 0) { red[wv] = s; red[4 + wv] = sq; }
  __syncthreads();
  s = red[0] + red[1] + red[2] + red[3];
  sq = red[4] + red[5] + red[6] + red[7];
  float mu = s * (1.0f / 512.0f);
  float var = sq * (1.0f / 512.0f) - mu * mu;
  float rs = rsqrtf(var + 1e-5f);
  float y0 = (v0 - mu) * rs * gamma[t] + beta[t];
  float y1 = (v1 - mu) * rs * gamma[t + 256] + beta[t + 256];
  ushort h0 = f2bf(y0), h1 = f2bf(y1);
  xkv_[(size_t)row * 1024 + t] = h0;
  xkv_[(size_t)row * 1024 + t + 256] = h1;
  xkv_[(size_t)row * 1024 + 512 + t] = f2bf(y0 - bf2f(h0));
  xkv_[(size_t)row * 1024 + 512 + t + 256] = f2bf(y1 - bf2f(h1));
}

// ---------------- MFMA flash attention: 128 q/block, DMA staging, dbuf ----------------
__global__ __launch_bounds__(256, 2) void attn_kernel(
    const ushort* __restrict__ Qs, const ushort* __restrict__ Kq,
    const ushort* __restrict__ Vt, ushort* __restrict__ attno) {
  __shared__ __align__(16) char arena[81920];
  ushort* KsL = (ushort*)arena;
  ushort* VtL = (ushort*)(arena + 32768);
  ushort* PL = (ushort*)(arena + 65536);
  float* ob = (float*)arena;

  int tid = threadIdx.x;
  int qb = blockIdx.x, h = blockIdx.y, b = blockIdx.z;
  int n0 = qb * 128, bh = b * 8 + h;
  int lane = tid & 63, w = tid >> 6;
  int q15 = lane & 15, g = lane >> 4;

  const ushort* kbase = Kq + (size_t)bh * 256 * 128;
  const ushort* vbase = Vt + (size_t)bh * 64 * 512;

  bf16x8 qf[2][2][2];
#pragma unroll
  for (int set = 0; set < 2; ++set) {
    const ushort* qptr =
        Qs + ((size_t)(b * 4096 + n0 + set * 64 + w * 16 + q15) * 8 + h) * 128;
#pragma unroll
    for (int s = 0; s < 2; ++s)
#pragma unroll
      for (int kb = 0; kb < 2; ++kb)
        qf[set][s][kb] = *(const bf16x8*)(qptr + s * 64 + kb * 32 + g * 8);
  }

  f32x4 accO[2][4];
#pragma unroll
  for (int set = 0; set < 2; ++set)
#pragma unroll
    for (int t = 0; t < 4; ++t) accO[set][t] = (f32x4){0.f, 0.f, 0.f, 0.f};
  float m[2] = {-1e30f, -1e30f}, l[2] = {0.f, 0.f};

#define STAGE_A(cc, buf)                                                     \
  {                                                                          \
    _Pragma("unroll") for (int i = 0; i < 4; ++i) {                          \
      int rb_ = w * 16 + i * 4;                                              \
      int r_ = rb_ + (lane >> 4);                                            \
      int sb_ = (lane & 15) ^ (r_ & 7);                                      \
      gload16(kbase + (size_t)((cc) * 64 + r_) * 128 + (sb_ << 3),           \
              KsL + (buf) * 8192 + rb_ * 128);                               \
      gload16(vbase + (size_t)r_ * 512 + ((sb_ >> 3) << 8) + (cc) * 64 +     \
                  ((sb_ & 7) << 3),                                          \
              VtL + (buf) * 8192 + rb_ * 128);                               \
    }                                                                        \
  }

  STAGE_A(0, 0);
  __syncthreads();

  for (int c = 0; c < 4; ++c) {
    int buf = c & 1;
    if (c < 3) STAGE_A(c + 1, buf ^ 1);
    const ushort* Ks = KsL + buf * 8192;
    const ushort* Vs = VtL + buf * 8192;

    f32x4 accS[2][4];
#pragma unroll
    for (int set = 0; set < 2; ++set)
#pragma unroll
      for (int t = 0; t < 4; ++t) accS[set][t] = (f32x4){0.f, 0.f, 0.f, 0.f};
#pragma unroll
    for (int kb = 0; kb < 2; ++kb) {
      bf16x8 ak[4], al[4];
#pragma unroll
      for (int t = 0; t < 4; ++t) {
        int kkr = t * 16 + q15;
        ak[t] = *(const bf16x8*)&Ks[kkr * 128 + (((kb * 4 + g) ^ (kkr & 7)) << 3)];
        al[t] = *(const bf16x8*)&Ks[kkr * 128 + (((8 + kb * 4 + g) ^ (kkr & 7)) << 3)];
      }
#pragma unroll
      for (int set = 0; set < 2; ++set) {
#pragma unroll
        for (int t = 0; t < 4; ++t)
          accS[set][t] = __builtin_amdgcn_mfma_f32_16x16x32_bf16(
              ak[t], qf[set][0][kb], accS[set][t], 0, 0, 0);
#pragma unroll
        for (int t = 0; t < 4; ++t)
          accS[set][t] = __builtin_amdgcn_mfma_f32_16x16x32_bf16(
              ak[t], qf[set][1][kb], accS[set][t], 0, 0, 0);
#pragma unroll
        for (int t = 0; t < 4; ++t)
          accS[set][t] = __builtin_amdgcn_mfma_f32_16x16x32_bf16(
              al[t], qf[set][0][kb], accS[set][t], 0, 0, 0);
      }
    }

#pragma unroll
    for (int set = 0; set < 2; ++set) {
      int qrowL = set * 64 + w * 16 + q15;
      float mx = -1e30f;
#pragma unroll
      for (int t = 0; t < 4; ++t)
#pragma unroll
        for (int r = 0; r < 4; ++r) mx = fmaxf(mx, accS[set][t][r]);
      mx = fmaxf(mx, __shfl_xor(mx, 16));
      mx = fmaxf(mx, __shfl_xor(mx, 32));
      float mn = fmaxf(m[set], mx);
      float fac = __expf(m[set] - mn);
      m[set] = mn;
      float sum = 0.f;
      ushort ph[4][4];
#pragma unroll
      for (int t = 0; t < 4; ++t)
#pragma unroll
        for (int r = 0; r < 4; ++r) {
          float p = __expf(accS[set][t][r] - mn);
          ushort hp = f2bf(p);
          ph[t][r] = hp;
          sum += bf2f(hp);
        }
      sum += __shfl_xor(sum, 16);
      sum += __shfl_xor(sum, 32);
      l[set] = l[set] * fac + sum;
#pragma unroll
      for (int t = 0; t < 4; ++t) {
        accO[set][t][0] *= fac; accO[set][t][1] *= fac;
        accO[set][t][2] *= fac; accO[set][t][3] *= fac;
      }
#pragma unroll
      for (int t = 0; t < 4; ++t)
#pragma unroll
        for (int rp = 0; rp < 4; rp += 2) {
          uint u = ph[t][rp] | ((uint)ph[t][rp + 1] << 16);
          int kkl = t * 16 + g * 4 + rp;
          int blk = kkl >> 3, off = kkl & 7;
          *(uint*)((char*)PL + qrowL * 128 + ((blk ^ (q15 & 7)) << 4) + off * 2) = u;
        }
    }
    __syncthreads();

    bf16x8 pf[2][2];
#pragma unroll
    for (int set = 0; set < 2; ++set) {
      int qrowL = set * 64 + w * 16 + q15;
#pragma unroll
      for (int kb = 0; kb < 2; ++kb)
        pf[set][kb] = *(const bf16x8*)((char*)PL + qrowL * 128 +
                                       (((kb * 4 + g) ^ (q15 & 7)) << 4));
    }
#pragma unroll
    for (int s = 0; s < 2; ++s)
#pragma unroll
      for (int kb = 0; kb < 2; ++kb)
#pragma unroll
        for (int t = 0; t < 4; ++t) {
          int d = t * 16 + q15;
          bf16x8 vf =
              *(const bf16x8*)&Vs[d * 128 + (((s * 8 + kb * 4 + g) ^ (d & 7)) << 3)];
          accO[0][t] = __builtin_amdgcn_mfma_f32_16x16x32_bf16(vf, pf[0][kb],
                                                               accO[0][t], 0, 0, 0);
          accO[1][t] = __builtin_amdgcn_mfma_f32_16x16x32_bf16(vf, pf[1][kb],
                                                               accO[1][t], 0, 0, 0);
        }
    __syncthreads();
  }
#undef STAGE_A

#pragma unroll
  for (int set = 0; set < 2; ++set) {
    if (set) __syncthreads();
    float inv = 1.0f / l[set];
#pragma unroll
    for (int t = 0; t < 4; ++t)
#pragma unroll
      for (int r = 0; r < 4; ++r)
        ob[(t * 16 + g * 4 + r) * 68 + w * 16 + q15] = accO[set][t][r] * inv;
    __syncthreads();
#pragma unroll
    for (int i = 0; i < 2; ++i) {
      int idx = tid + i * 256;
      int qq = idx >> 3, d8 = (idx & 7) << 3;
      ushort hh[8], ll[8];
#pragma unroll
      for (int jj = 0; jj < 8; ++jj) {
        float v = ob[(d8 + jj) * 68 + qq];
        hh[jj] = f2bf(v);
        ll[jj] = f2bf(v - bf2f(hh[jj]));
      }
      uint4 hp, lp;
      hp.x = hh[0] | ((uint)hh[1] << 16); hp.y = hh[2] | ((uint)hh[3] << 16);
      hp.z = hh[4] | ((uint)hh[5] << 16); hp.w = hh[6] | ((uint)hh[7] << 16);
      lp.x = ll[0] | ((uint)ll[1] << 16); lp.y = ll[2] | ((uint)ll[3] << 16);
      lp.z = ll[4] | ((uint)ll[5] << 16); lp.w = ll[6] | ((uint)ll[7] << 16);
      size_t rowb = (size_t)(b * 4096 + n0 + set * 64 + qq) * 1024 + h * 64 + d8;
      *(uint4*)(attno + rowb) = hp;
      *(uint4*)(attno + rowb + 512) = lp;
    }
  }
}

// ---------------- launch ----------------
extern "C" void kernel_launch(void* const* d_in, const int* in_sizes, int n_in,
                              void* d_out, int out_size, void* d_ws, size_t ws_size,
                              hipStream_t stream) {
  const float* x     = (const float*)d_in[0];
  const float* Wq    = (const float*)d_in[1];
  const float* bq    = (const float*)d_in[2];
  const float* Wk    = (const float*)d_in[3];
  const float* bk    = (const float*)d_in[4];
  const float* Wv    = (const float*)d_in[5];
  const float* bv    = (const float*)d_in[6];
  const float* Wp    = (const float*)d_in[7];
  const float* bp    = (const float*)d_in[8];
  const float* Wsr   = (const float*)d_in[9];
  const float* bsr   = (const float*)d_in[10];
  const float* gamma = (const float*)d_in[11];
  const float* beta  = (const float*)d_in[12];

  float* ws = (float*)d_ws;
  // Fused layout needs conv_part AND Qsplit live simultaneously.
  // Fused end = 31,982,592 floats = 127,930,368 bytes.
  bool bigws = ws_size >= 127930368ull;

  ushort* xq     = (ushort*)ws;                 // regionA; attno_ later
  ushort* attno_ = (ushort*)ws;
  float*  conv_part = ws + 8388608;             // [16][1024][512] f32 = 8,388,608 fl
  ushort* Qsplit = bigws ? (ushort*)(ws + 16777216)   // 16,777,216 us = 8,388,608 fl
                         : (ushort*)(ws + 8388608);   // aliases conv_part (compact)
  size_t tail = bigws ? 25165824 : 16777216;
  ushort* Wsr_ = (ushort*)(ws + tail);          // 8,388,608 us = 4,194,304 fl
  float*  rest = ws + tail + 4194304;
  // NOTE: sizes below are in FLOAT units (ushort count / 2) — round-9 bug was /4.
  ushort* Wq_  = (ushort*)rest;                 // 524,288 us = 262,144 fl
  ushort* Wp_  = (ushort*)(rest + 262144);      // 524,288 us = 262,144 fl
  ushort* Wkv_ = (ushort*)(rest + 524288);      // 1,048,576 us = 524,288 fl
  ushort* xkv_ = (ushort*)(rest + 1048576);     // 1,048,576 us = 524,288 fl
  ushort* Kq   = (ushort*)(rest + 1572864);     // 1,048,576 us = 524,288 fl
  ushort* Vt   = (ushort*)(rest + 2097152);     // 1,048,576 us = 524,288 fl
  float*  bkv  = rest + 2621440;                // 1,024 fl
  float* outp = (float*)d_out;

  prep_kernel<<<8705, 256, 0, stream>>>(x, Wq, Wp, Wk, Wv, Wsr, bk, bv,
                                        xq, Wq_, Wp_, Wkv_, Wsr_, bkv);
  if (bigws) {
    // conv + q-proj concurrent in one 1024-block launch
    cq_kernel<<<1024, 256, 0, stream>>>(xq, Wsr_, conv_part, Wq_, bq, Qsplit, 0);
    ln_kernel<<<1024, 256, 0, stream>>>(conv_part, bsr, gamma, beta, xkv_);
  } else {
    // compact: conv -> ln -> q-proj (Qsplit overwrites conv_part after ln)
    cq_kernel<<<512, 256, 0, stream>>>(xq, Wsr_, conv_part, Wq_, bq, Qsplit, 0);
    ln_kernel<<<1024, 256, 0, stream>>>(conv_part, bsr, gamma, beta, xkv_);
    cq_kernel<<<512, 256, 0, stream>>>(xq, Wsr_, conv_part, Wq_, bq, Qsplit, 512);
  }
  kvproj_kernel<<<64, 256, 0, stream>>>(xkv_, Wkv_, bkv, Kq, Vt);
  attn_kernel<<<dim3(32, 8, 4), 256, 0, stream>>>(Qsplit, Kq, Vt, attno_);
  gemm_out_kernel<<<512, 256, 0, stream>>>(attno_, Wp_, bp, outp);
}

// Round 11
// 172.264 us; speedup vs baseline: 1.0789x; 1.0789x over previous
//
#include <hip/hip_runtime.h>

// B=4, H=W=64, N=4096, C=512, HEAD=8, dh=64, SR=4, Nk=256
// Split-bf16: val = hi + lo (both bf16).
// TERMS=3: aH*bH + aL*bH + aH*bL (drops only lo*lo ~4e-6 rel) — conv, kv-proj.
// TERMS=2: aH*bH + aL*bH (drops weight-lo term, ~4e-4 abs) — q-proj, out-proj
//          (error budget verified: absmax floor 2.44e-4, threshold 1.26e-3).

typedef __bf16 bf16x8 __attribute__((ext_vector_type(8)));
typedef float f32x4 __attribute__((ext_vector_type(4)));

__device__ __forceinline__ ushort f2bf(float v) {
  uint u = __float_as_uint(v);
  return (ushort)((u + 0x7FFFu + ((u >> 16) & 1u)) >> 16);
}
__device__ __forceinline__ float bf2f(ushort h) {
  return __uint_as_float((uint)h << 16);
}
__device__ __forceinline__ void gload16(const void* g, void* l) {
  __builtin_amdgcn_global_load_lds(
      (const __attribute__((address_space(1))) void*)g,
      (__attribute__((address_space(3))) void*)l, 16, 0, 0);
}
// bijective XCD swizzle for nwg % 8 == 0
__device__ __forceinline__ int xcd_swz(int bid, int nwg) {
  int cpx = nwg >> 3;
  return (bid & 7) * cpx + (bid >> 3);
}

// ---------------- fused prep: convert x, W's, Wsr, biases ----------------
__global__ __launch_bounds__(256) void prep_kernel(
    const float* __restrict__ x, const float* __restrict__ Wq,
    const float* __restrict__ Wp, const float* __restrict__ Wk,
    const float* __restrict__ Wv, const float* __restrict__ Wsr,
    const float* __restrict__ bk, const float* __restrict__ bv,
    ushort* __restrict__ xq, ushort* __restrict__ Wq_,
    ushort* __restrict__ Wp_, ushort* __restrict__ Wkv_,
    ushort* __restrict__ Wsr_, float* __restrict__ bkv) {
  __shared__ float t[32][33];
  int bid = blockIdx.x, tid = threadIdx.x;
  if (bid < 4096 + 512) {
    const float* src;
    ushort* dst;
    int gid;
    if (bid < 4096) {
      src = x; dst = xq; gid = bid * 256 + tid;
    } else {
      int z = (bid - 4096) >> 7;
      src = (z == 0) ? Wq : (z == 1) ? Wp : (z == 2) ? Wk : Wv;
      dst = (z == 0) ? Wq_ : (z == 1) ? Wp_ : (z == 2) ? Wkv_ : (Wkv_ + 512 * 1024);
      gid = ((bid - 4096) & 127) * 256 + tid;
    }
    int row = gid >> 6, c8 = (gid & 63) << 3;
    float4 a = *(const float4*)(src + (size_t)row * 512 + c8);
    float4 b = *(const float4*)(src + (size_t)row * 512 + c8 + 4);
    ushort h[8], l[8];
    float vv[8] = {a.x, a.y, a.z, a.w, b.x, b.y, b.z, b.w};
#pragma unroll
    for (int e = 0; e < 8; ++e) { h[e] = f2bf(vv[e]); l[e] = f2bf(vv[e] - bf2f(h[e])); }
    uint4 hp, lp;
    hp.x = h[0] | ((uint)h[1] << 16); hp.y = h[2] | ((uint)h[3] << 16);
    hp.z = h[4] | ((uint)h[5] << 16); hp.w = h[6] | ((uint)h[7] << 16);
    lp.x = l[0] | ((uint)l[1] << 16); lp.y = l[2] | ((uint)l[3] << 16);
    lp.z = l[4] | ((uint)l[5] << 16); lp.w = l[6] | ((uint)l[7] << 16);
    *(uint4*)(dst + (size_t)row * 1024 + c8) = hp;
    *(uint4*)(dst + (size_t)row * 1024 + 512 + c8) = lp;
  } else if (bid < 4096 + 512 + 4096) {
    int tb = bid - 4608;
    int z = tb >> 8, rem = tb & 255;
    int ci0 = (rem >> 4) << 5, co0 = (rem & 15) << 5;
    int tx = tid & 31, ty = tid >> 5;
#pragma unroll
    for (int i = 0; i < 32; i += 8)
      t[ty + i][tx] = Wsr[((size_t)z * 512 + ci0 + ty + i) * 512 + co0 + tx];
    __syncthreads();
#pragma unroll
    for (int i = 0; i < 32; i += 8) {
      float v = t[tx][ty + i];
      int co = co0 + ty + i, ci = ci0 + tx;
      ushort h = f2bf(v), l = f2bf(v - bf2f(h));
      Wsr_[((size_t)z * 512 + co) * 1024 + ci] = h;
      Wsr_[((size_t)z * 512 + co) * 1024 + 512 + ci] = l;
    }
  } else {
    bkv[tid] = bk[tid]; bkv[tid + 256] = bk[tid + 256];
    bkv[tid + 512] = bv[tid]; bkv[tid + 768] = bv[tid + 256];
  }
}

// ---------------- MFMA GEMM body: double-buffered 2-phase K-loop ----------------
// TERMS=3 -> 24 K-steps (logical K'=1536); TERMS=2 -> 16 K-steps (K'=1024).
// Section maps (identical formulas serve both):
//   ap = kk - (kk>=1024?1024:0)  -> A: hi, lo, [hi]
//   bp = kk - (kk>=512?512:0)    -> B: hi, hi, [lo]
// EPI=0: C fp32 + bias. EPI=1: Qsplit layout (LDS-coalesced). EPI=2: Kq/Vt scatter.
template <int EPI, int TERMS>
__device__ __forceinline__ void gemm_body(
    const ushort* __restrict__ A, const ushort* __restrict__ Bw,
    const float* __restrict__ bias, float* __restrict__ C,
    ushort* __restrict__ Qs, ushort* __restrict__ Kq, ushort* __restrict__ Vt,
    int N, int bx, int by, ushort* lds) {
  constexpr int NS = TERMS * 8;  // K-steps
  int tid = threadIdx.x;
  int lane = tid & 63, w = tid >> 6;
  int wr = w >> 1, wc = w & 1;
  int l15 = lane & 15, g = lane >> 4;
  int srow = lane >> 3;
  int scol = (lane & 7) ^ srow;

  const ushort* aBase = A + (size_t)(by * 128 + w * 32 + srow) * 1024 + scol * 8;
  const ushort* bBase = Bw + (size_t)(bx * 128 + w * 32 + srow) * 1024 + scol * 8;

  f32x4 acc[4][4];
#pragma unroll
  for (int i = 0; i < 4; ++i)
#pragma unroll
    for (int j = 0; j < 4; ++j) acc[i][j] = (f32x4){0.f, 0.f, 0.f, 0.f};

#define STAGE_G(ks, buf)                                              \
  {                                                                   \
    int kk = (ks) * 64;                                               \
    int ap = kk - (kk >= 1024 ? 1024 : 0);                            \
    int bp = kk - (kk >= 512 ? 512 : 0);                              \
    ushort* aD = lds + (buf) * 16384 + w * 2048;                      \
    ushort* bD = lds + (buf) * 16384 + 8192 + w * 2048;               \
    _Pragma("unroll") for (int t = 0; t < 4; ++t) {                   \
      gload16(aBase + (size_t)t * 8192 + ap, aD + t * 512);           \
      gload16(bBase + (size_t)t * 8192 + bp, bD + t * 512);           \
    }                                                                 \
  }

#define COMPUTE_G(buf)                                                         \
  {                                                                            \
    const ushort* As = lds + (buf) * 16384;                                    \
    const ushort* Bs = As + 8192;                                              \
    _Pragma("unroll") for (int kk2 = 0; kk2 < 2; ++kk2) {                      \
      int rb = kk2 * 4 + g;                                                    \
      bf16x8 af[4], bg[4];                                                     \
      _Pragma("unroll") for (int i = 0; i < 4; ++i) {                          \
        int row = wr * 64 + i * 16 + l15;                                      \
        af[i] = *(const bf16x8*)&As[row * 64 + ((rb ^ (row & 7)) << 3)];       \
      }                                                                        \
      _Pragma("unroll") for (int j = 0; j < 4; ++j) {                          \
        int col = wc * 64 + j * 16 + l15;                                      \
        bg[j] = *(const bf16x8*)&Bs[col * 64 + ((rb ^ (col & 7)) << 3)];       \
      }                                                                        \
      _Pragma("unroll") for (int i = 0; i < 4; ++i)                            \
        _Pragma("unroll") for (int j = 0; j < 4; ++j)                          \
          acc[i][j] =                                                          \
              __builtin_amdgcn_mfma_f32_16x16x32_bf16(af[i], bg[j], acc[i][j], \
                                                      0, 0, 0);                \
    }                                                                          \
  }

  STAGE_G(0, 0);
  __syncthreads();
  for (int ks = 0; ks < NS - 1; ++ks) {
    STAGE_G(ks + 1, (ks + 1) & 1);
    COMPUTE_G(ks & 1);
    __syncthreads();
  }
  COMPUTE_G((NS - 1) & 1);

#undef STAGE_G
#undef COMPUTE_G

  if (EPI == 0) {
#pragma unroll
    for (int j = 0; j < 4; ++j) {
      int col = bx * 128 + wc * 64 + j * 16 + l15;
      float bj = bias ? bias[col] : 0.f;
#pragma unroll
      for (int i = 0; i < 4; ++i) {
        int row0 = by * 128 + wr * 64 + i * 16 + g * 4;
#pragma unroll
        for (int r = 0; r < 4; ++r)
          C[(size_t)(row0 + r) * N + col] = acc[i][j][r] + bj;
      }
    }
  } else if (EPI == 1) {
    __syncthreads();
#pragma unroll
    for (int j = 0; j < 4; ++j) {
      int cl = wc * 64 + j * 16 + l15;
      float bj = bias[bx * 128 + cl];
#pragma unroll
      for (int i = 0; i < 4; ++i) {
        int rl0 = wr * 64 + i * 16 + g * 4;
#pragma unroll
        for (int r = 0; r < 4; ++r) {
          float v = (acc[i][j][r] + bj) * 0.125f;
          ushort h = f2bf(v), lo = f2bf(v - bf2f(h));
          lds[(rl0 + r) * 128 + cl] = h;
          lds[16384 + (rl0 + r) * 128 + cl] = lo;
        }
      }
    }
    __syncthreads();
#pragma unroll
    for (int it = 0; it < 8; ++it) {
      int c = tid + it * 256;
      int r = c >> 4, ck = c & 15;
      int grow = by * 128 + r;
      size_t base = ((size_t)grow * 8 + bx * 2 + (ck >> 3)) * 128 + (ck & 7) * 8;
      *(uint4*)(Qs + base) = *(const uint4*)&lds[r * 128 + ck * 8];
      *(uint4*)(Qs + base + 64) = *(const uint4*)&lds[16384 + r * 128 + ck * 8];
    }
  } else {
    // EPI=2: kv epilogue — scatter split-bf16 directly into Kq / Vt layouts.
#pragma unroll
    for (int j = 0; j < 4; ++j) {
      int col = bx * 128 + wc * 64 + j * 16 + l15;
      float bj = bias[col];
      bool isK = col < 512;
      int cp = isK ? col : col - 512;
      int hh = cp >> 6, d = cp & 63;
#pragma unroll
      for (int i = 0; i < 4; ++i) {
        int row0 = by * 128 + wr * 64 + i * 16 + g * 4;
#pragma unroll
        for (int r = 0; r < 4; ++r) {
          int row = row0 + r;
          int b = row >> 8, kk = row & 255;
          float v = acc[i][j][r] + bj;
          ushort h = f2bf(v), lo = f2bf(v - bf2f(h));
          if (isK) {
            size_t base = ((size_t)((b * 8 + hh) * 256) + kk) * 128 + d;
            Kq[base] = h; Kq[base + 64] = lo;
          } else {
            size_t base = ((size_t)((b * 8 + hh) * 64) + d) * 512 + kk;
            Vt[base] = h; Vt[base + 256] = lo;
          }
        }
      }
    }
  }
}

// ---------------- conv body (split-16, one tap per z; TERMS=3) ----------------
__device__ __forceinline__ void conv_body(
    const ushort* __restrict__ xq, const ushort* __restrict__ Wsr_,
    float* __restrict__ part, int bx, int by, int z, ushort* lds) {
  int kh = z >> 2, kw = z & 3;
  int tid = threadIdx.x;
  int lane = tid & 63, w = tid >> 6;
  int wr = w >> 1, wc = w & 1;
  int l15 = lane & 15, g = lane >> 4;
  int srow = lane >> 3;
  int scol = (lane & 7) ^ srow;

  const ushort* aBase[4];
#pragma unroll
  for (int t = 0; t < 4; ++t) {
    int gm = by * 128 + w * 32 + t * 8 + srow;
    int xr = (gm >> 8) * 4096 + ((((gm >> 4) & 15) << 2) + kh) * 64 +
             ((gm & 15) << 2) + kw;
    aBase[t] = xq + (size_t)xr * 1024 + scol * 8;
  }
  const ushort* bBase =
      Wsr_ + ((size_t)z * 512 + bx * 128 + w * 32 + srow) * 1024 + scol * 8;

  f32x4 acc[4][4];
#pragma unroll
  for (int i = 0; i < 4; ++i)
#pragma unroll
    for (int j = 0; j < 4; ++j) acc[i][j] = (f32x4){0.f, 0.f, 0.f, 0.f};

#define STAGE_C(ks, buf)                                              \
  {                                                                   \
    int kk = (ks) * 64;                                               \
    int ap = kk - (kk >= 1024 ? 1024 : 0);                            \
    int bp = kk - (kk >= 512 ? 512 : 0);                              \
    ushort* aD = lds + (buf) * 16384 + w * 2048;                      \
    ushort* bD = lds + (buf) * 16384 + 8192 + w * 2048;               \
    _Pragma("unroll") for (int t = 0; t < 4; ++t) {                   \
      gload16(aBase[t] + ap, aD + t * 512);                           \
      gload16(bBase + (size_t)t * 8192 + bp, bD + t * 512);           \
    }                                                                 \
  }

#define COMPUTE_C(buf)                                                         \
  {                                                                            \
    const ushort* As = lds + (buf) * 16384;                                    \
    const ushort* Bs = As + 8192;                                              \
    _Pragma("unroll") for (int kk2 = 0; kk2 < 2; ++kk2) {                      \
      int rb = kk2 * 4 + g;                                                    \
      bf16x8 af[4], bg[4];                                                     \
      _Pragma("unroll") for (int i = 0; i < 4; ++i) {                          \
        int row = wr * 64 + i * 16 + l15;                                      \
        af[i] = *(const bf16x8*)&As[row * 64 + ((rb ^ (row & 7)) << 3)];       \
      }                                                                        \
      _Pragma("unroll") for (int j = 0; j < 4; ++j) {                          \
        int col = wc * 64 + j * 16 + l15;                                      \
        bg[j] = *(const bf16x8*)&Bs[col * 64 + ((rb ^ (col & 7)) << 3)];       \
      }                                                                        \
      _Pragma("unroll") for (int i = 0; i < 4; ++i)                            \
        _Pragma("unroll") for (int j = 0; j < 4; ++j)                          \
          acc[i][j] =                                                          \
              __builtin_amdgcn_mfma_f32_16x16x32_bf16(af[i], bg[j], acc[i][j], \
                                                      0, 0, 0);                \
    }                                                                          \
  }

  STAGE_C(0, 0);
  __syncthreads();
  for (int ks = 0; ks < 23; ++ks) {
    STAGE_C(ks + 1, (ks + 1) & 1);
    COMPUTE_C(ks & 1);
    __syncthreads();
  }
  COMPUTE_C(1);

#undef STAGE_C
#undef COMPUTE_C

  float* Cp = part + (size_t)z * 524288;
#pragma unroll
  for (int j = 0; j < 4; ++j) {
    int col = bx * 128 + wc * 64 + j * 16 + l15;
#pragma unroll
    for (int i = 0; i < 4; ++i) {
      int row0 = by * 128 + wr * 64 + i * 16 + g * 4;
#pragma unroll
      for (int r = 0; r < 4; ++r)
        Cp[(size_t)(row0 + r) * 512 + col] = acc[i][j][r];
    }
  }
}

// conv (work-ids 0..511, TERMS=3) + q-proj (512..1023, TERMS=2)
__global__ __launch_bounds__(256) void cq_kernel(
    const ushort* __restrict__ xq, const ushort* __restrict__ Wsr_,
    float* __restrict__ part, const ushort* __restrict__ Wq_,
    const float* __restrict__ bq, ushort* __restrict__ Qs, int base) {
  __shared__ __align__(16) ushort lds[32768];
  int bid = xcd_swz(blockIdx.x, gridDim.x) + base;
  if (bid < 512) {
    conv_body(xq, Wsr_, part, bid & 3, (bid >> 2) & 7, bid >> 5, lds);
  } else {
    int b2 = bid - 512;
    gemm_body<1, 2>(xq, Wq_, bq, nullptr, Qs, nullptr, nullptr, 512,
                    b2 & 3, b2 >> 2, lds);
  }
}

// kv-proj: 64 blocks, writes Kq/Vt directly (EPI=2, TERMS=3)
__global__ __launch_bounds__(256) void kvproj_kernel(
    const ushort* __restrict__ xkv_, const ushort* __restrict__ Wkv_,
    const float* __restrict__ bkv, ushort* __restrict__ Kq,
    ushort* __restrict__ Vt) {
  __shared__ __align__(16) ushort lds[32768];
  int bid = xcd_swz(blockIdx.x, 64);
  gemm_body<2, 3>(xkv_, Wkv_, bkv, nullptr, nullptr, Kq, Vt, 1024,
                  bid & 7, bid >> 3, lds);
}

// out-proj (TERMS=2)
__global__ __launch_bounds__(256) void gemm_out_kernel(
    const ushort* __restrict__ A, const ushort* __restrict__ Bw,
    const float* __restrict__ bias, float* __restrict__ C) {
  __shared__ __align__(16) ushort lds[32768];
  int bid = xcd_swz(blockIdx.x, 512);
  gemm_body<0, 2>(A, Bw, bias, C, nullptr, nullptr, nullptr, 512,
                  bid & 3, bid >> 2, lds);
}

// ---------------- partial-sum(16) + bias + LayerNorm -> split-bf16 ----------------
__global__ __launch_bounds__(256) void ln_kernel(
    const float* __restrict__ part, const float* __restrict__ bsr,
    const float* __restrict__ gamma, const float* __restrict__ beta,
    ushort* __restrict__ xkv_) {
  int row = blockIdx.x;
  int t = threadIdx.x;
  float v0 = bsr[t], v1 = bsr[t + 256];
  for (int p = 0; p < 16; ++p) {
    v0 += part[(size_t)p * 524288 + (size_t)row * 512 + t];
    v1 += part[(size_t)p * 524288 + (size_t)row * 512 + t + 256];
  }
  float s = v0 + v1, sq = v0 * v0 + v1 * v1;
#pragma unroll
  for (int o = 1; o < 64; o <<= 1) {
    s += __shfl_xor(s, o);
    sq += __shfl_xor(sq, o);
  }
  __shared__ float red[8];
  int wv = t >> 6;
  if ((t & 63) == 0) { red[wv] = s; red[4 + wv] = sq; }
  __syncthreads();
  s = red[0] + red[1] + red[2] + red[3];
  sq = red[4] + red[5] + red[6] + red[7];
  float mu = s * (1.0f / 512.0f);
  float var = sq * (1.0f / 512.0f) - mu * mu;
  float rs = rsqrtf(var + 1e-5f);
  float y0 = (v0 - mu) * rs * gamma[t] + beta[t];
  float y1 = (v1 - mu) * rs * gamma[t + 256] + beta[t + 256];
  ushort h0 = f2bf(y0), h1 = f2bf(y1);
  xkv_[(size_t)row * 1024 + t] = h0;
  xkv_[(size_t)row * 1024 + t + 256] = h1;
  xkv_[(size_t)row * 1024 + 512 + t] = f2bf(y0 - bf2f(h0));
  xkv_[(size_t)row * 1024 + 512 + t + 256] = f2bf(y1 - bf2f(h1));
}

// ---------------- MFMA flash attention: 128 q/block, DMA staging, dbuf ----------------
__global__ __launch_bounds__(256, 2) void attn_kernel(
    const ushort* __restrict__ Qs, const ushort* __restrict__ Kq,
    const ushort* __restrict__ Vt, ushort* __restrict__ attno) {
  __shared__ __align__(16) char arena[81920];
  ushort* KsL = (ushort*)arena;
  ushort* VtL = (ushort*)(arena + 32768);
  ushort* PL = (ushort*)(arena + 65536);
  float* ob = (float*)arena;

  int tid = threadIdx.x;
  int qb = blockIdx.x, h = blockIdx.y, b = blockIdx.z;
  int n0 = qb * 128, bh = b * 8 + h;
  int lane = tid & 63, w = tid >> 6;
  int q15 = lane & 15, g = lane >> 4;

  const ushort* kbase = Kq + (size_t)bh * 256 * 128;
  const ushort* vbase = Vt + (size_t)bh * 64 * 512;

  bf16x8 qf[2][2][2];
#pragma unroll
  for (int set = 0; set < 2; ++set) {
    const ushort* qptr =
        Qs + ((size_t)(b * 4096 + n0 + set * 64 + w * 16 + q15) * 8 + h) * 128;
#pragma unroll
    for (int s = 0; s < 2; ++s)
#pragma unroll
      for (int kb = 0; kb < 2; ++kb)
        qf[set][s][kb] = *(const bf16x8*)(qptr + s * 64 + kb * 32 + g * 8);
  }

  f32x4 accO[2][4];
#pragma unroll
  for (int set = 0; set < 2; ++set)
#pragma unroll
    for (int t = 0; t < 4; ++t) accO[set][t] = (f32x4){0.f, 0.f, 0.f, 0.f};
  float m[2] = {-1e30f, -1e30f}, l[2] = {0.f, 0.f};

#define STAGE_A(cc, buf)                                                     \
  {                                                                          \
    _Pragma("unroll") for (int i = 0; i < 4; ++i) {                          \
      int rb_ = w * 16 + i * 4;                                              \
      int r_ = rb_ + (lane >> 4);                                            \
      int sb_ = (lane & 15) ^ (r_ & 7);                                      \
      gload16(kbase + (size_t)((cc) * 64 + r_) * 128 + (sb_ << 3),           \
              KsL + (buf) * 8192 + rb_ * 128);                               \
      gload16(vbase + (size_t)r_ * 512 + ((sb_ >> 3) << 8) + (cc) * 64 +     \
                  ((sb_ & 7) << 3),                                          \
              VtL + (buf) * 8192 + rb_ * 128);                               \
    }                                                                        \
  }

  STAGE_A(0, 0);
  __syncthreads();

  for (int c = 0; c < 4; ++c) {
    int buf = c & 1;
    if (c < 3) STAGE_A(c + 1, buf ^ 1);
    const ushort* Ks = KsL + buf * 8192;
    const ushort* Vs = VtL + buf * 8192;

    f32x4 accS[2][4];
#pragma unroll
    for (int set = 0; set < 2; ++set)
#pragma unroll
      for (int t = 0; t < 4; ++t) accS[set][t] = (f32x4){0.f, 0.f, 0.f, 0.f};
#pragma unroll
    for (int kb = 0; kb < 2; ++kb) {
      bf16x8 ak[4], al[4];
#pragma unroll
      for (int t = 0; t < 4; ++t) {
        int kkr = t * 16 + q15;
        ak[t] = *(const bf16x8*)&Ks[kkr * 128 + (((kb * 4 + g) ^ (kkr & 7)) << 3)];
        al[t] = *(const bf16x8*)&Ks[kkr * 128 + (((8 + kb * 4 + g) ^ (kkr & 7)) << 3)];
      }
#pragma unroll
      for (int set = 0; set < 2; ++set) {
#pragma unroll
        for (int t = 0; t < 4; ++t)
          accS[set][t] = __builtin_amdgcn_mfma_f32_16x16x32_bf16(
              ak[t], qf[set][0][kb], accS[set][t], 0, 0, 0);
#pragma unroll
        for (int t = 0; t < 4; ++t)
          accS[set][t] = __builtin_amdgcn_mfma_f32_16x16x32_bf16(
              ak[t], qf[set][1][kb], accS[set][t], 0, 0, 0);
#pragma unroll
        for (int t = 0; t < 4; ++t)
          accS[set][t] = __builtin_amdgcn_mfma_f32_16x16x32_bf16(
              al[t], qf[set][0][kb], accS[set][t], 0, 0, 0);
      }
    }

#pragma unroll
    for (int set = 0; set < 2; ++set) {
      int qrowL = set * 64 + w * 16 + q15;
      float mx = -1e30f;
#pragma unroll
      for (int t = 0; t < 4; ++t)
#pragma unroll
        for (int r = 0; r < 4; ++r) mx = fmaxf(mx, accS[set][t][r]);
      mx = fmaxf(mx, __shfl_xor(mx, 16));
      mx = fmaxf(mx, __shfl_xor(mx, 32));
      float mn = fmaxf(m[set], mx);
      float fac = __expf(m[set] - mn);
      m[set] = mn;
      float sum = 0.f;
      ushort ph[4][4];
#pragma unroll
      for (int t = 0; t < 4; ++t)
#pragma unroll
        for (int r = 0; r < 4; ++r) {
          float p = __expf(accS[set][t][r] - mn);
          ushort hp = f2bf(p);
          ph[t][r] = hp;
          sum += bf2f(hp);
        }
      sum += __shfl_xor(sum, 16);
      sum += __shfl_xor(sum, 32);
      l[set] = l[set] * fac + sum;
#pragma unroll
      for (int t = 0; t < 4; ++t) {
        accO[set][t][0] *= fac; accO[set][t][1] *= fac;
        accO[set][t][2] *= fac; accO[set][t][3] *= fac;
      }
#pragma unroll
      for (int t = 0; t < 4; ++t)
#pragma unroll
        for (int rp = 0; rp < 4; rp += 2) {
          uint u = ph[t][rp] | ((uint)ph[t][rp + 1] << 16);
          int kkl = t * 16 + g * 4 + rp;
          int blk = kkl >> 3, off = kkl & 7;
          *(uint*)((char*)PL + qrowL * 128 + ((blk ^ (q15 & 7)) << 4) + off * 2) = u;
        }
    }
    __syncthreads();

    bf16x8 pf[2][2];
#pragma unroll
    for (int set = 0; set < 2; ++set) {
      int qrowL = set * 64 + w * 16 + q15;
#pragma unroll
      for (int kb = 0; kb < 2; ++kb)
        pf[set][kb] = *(const bf16x8*)((char*)PL + qrowL * 128 +
                                       (((kb * 4 + g) ^ (q15 & 7)) << 4));
    }
#pragma unroll
    for (int s = 0; s < 2; ++s)
#pragma unroll
      for (int kb = 0; kb < 2; ++kb)
#pragma unroll
        for (int t = 0; t < 4; ++t) {
          int d = t * 16 + q15;
          bf16x8 vf =
              *(const bf16x8*)&Vs[d * 128 + (((s * 8 + kb * 4 + g) ^ (d & 7)) << 3)];
          accO[0][t] = __builtin_amdgcn_mfma_f32_16x16x32_bf16(vf, pf[0][kb],
                                                               accO[0][t], 0, 0, 0);
          accO[1][t] = __builtin_amdgcn_mfma_f32_16x16x32_bf16(vf, pf[1][kb],
                                                               accO[1][t], 0, 0, 0);
        }
    __syncthreads();
  }
#undef STAGE_A

#pragma unroll
  for (int set = 0; set < 2; ++set) {
    if (set) __syncthreads();
    float inv = 1.0f / l[set];
#pragma unroll
    for (int t = 0; t < 4; ++t)
#pragma unroll
      for (int r = 0; r < 4; ++r)
        ob[(t * 16 + g * 4 + r) * 68 + w * 16 + q15] = accO[set][t][r] * inv;
    __syncthreads();
#pragma unroll
    for (int i = 0; i < 2; ++i) {
      int idx = tid + i * 256;
      int qq = idx >> 3, d8 = (idx & 7) << 3;
      ushort hh[8], ll[8];
#pragma unroll
      for (int jj = 0; jj < 8; ++jj) {
        float v = ob[(d8 + jj) * 68 + qq];
        hh[jj] = f2bf(v);
        ll[jj] = f2bf(v - bf2f(hh[jj]));
      }
      uint4 hp, lp;
      hp.x = hh[0] | ((uint)hh[1] << 16); hp.y = hh[2] | ((uint)hh[3] << 16);
      hp.z = hh[4] | ((uint)hh[5] << 16); hp.w = hh[6] | ((uint)hh[7] << 16);
      lp.x = ll[0] | ((uint)ll[1] << 16); lp.y = ll[2] | ((uint)ll[3] << 16);
      lp.z = ll[4] | ((uint)ll[5] << 16); lp.w = ll[6] | ((uint)ll[7] << 16);
      size_t rowb = (size_t)(b * 4096 + n0 + set * 64 + qq) * 1024 + h * 64 + d8;
      *(uint4*)(attno + rowb) = hp;
      *(uint4*)(attno + rowb + 512) = lp;
    }
  }
}

// ---------------- launch ----------------
extern "C" void kernel_launch(void* const* d_in, const int* in_sizes, int n_in,
                              void* d_out, int out_size, void* d_ws, size_t ws_size,
                              hipStream_t stream) {
  const float* x     = (const float*)d_in[0];
  const float* Wq    = (const float*)d_in[1];
  const float* bq    = (const float*)d_in[2];
  const float* Wk    = (const float*)d_in[3];
  const float* bk    = (const float*)d_in[4];
  const float* Wv    = (const float*)d_in[5];
  const float* bv    = (const float*)d_in[6];
  const float* Wp    = (const float*)d_in[7];
  const float* bp    = (const float*)d_in[8];
  const float* Wsr   = (const float*)d_in[9];
  const float* bsr   = (const float*)d_in[10];
  const float* gamma = (const float*)d_in[11];
  const float* beta  = (const float*)d_in[12];

  float* ws = (float*)d_ws;
  // Fused layout end = 31,982,592 floats = 127,930,368 bytes.
  bool bigws = ws_size >= 127930368ull;

  ushort* xq     = (ushort*)ws;                 // regionA; attno_ later
  ushort* attno_ = (ushort*)ws;
  float*  conv_part = ws + 8388608;             // [16][1024][512] f32
  ushort* Qsplit = bigws ? (ushort*)(ws + 16777216)
                         : (ushort*)(ws + 8388608);   // aliases conv_part (compact)
  size_t tail = bigws ? 25165824 : 16777216;
  ushort* Wsr_ = (ushort*)(ws + tail);          // 8,388,608 us = 4,194,304 fl
  float*  rest = ws + tail + 4194304;
  ushort* Wq_  = (ushort*)rest;                 // 524,288 us = 262,144 fl
  ushort* Wp_  = (ushort*)(rest + 262144);      // 524,288 us = 262,144 fl
  ushort* Wkv_ = (ushort*)(rest + 524288);      // 1,048,576 us = 524,288 fl
  ushort* xkv_ = (ushort*)(rest + 1048576);     // 1,048,576 us = 524,288 fl
  ushort* Kq   = (ushort*)(rest + 1572864);     // 1,048,576 us = 524,288 fl
  ushort* Vt   = (ushort*)(rest + 2097152);     // 1,048,576 us = 524,288 fl
  float*  bkv  = rest + 2621440;                // 1,024 fl
  float* outp = (float*)d_out;

  prep_kernel<<<8705, 256, 0, stream>>>(x, Wq, Wp, Wk, Wv, Wsr, bk, bv,
                                        xq, Wq_, Wp_, Wkv_, Wsr_, bkv);
  if (bigws) {
    cq_kernel<<<1024, 256, 0, stream>>>(xq, Wsr_, conv_part, Wq_, bq, Qsplit, 0);
    ln_kernel<<<1024, 256, 0, stream>>>(conv_part, bsr, gamma, beta, xkv_);
  } else {
    cq_kernel<<<512, 256, 0, stream>>>(xq, Wsr_, conv_part, Wq_, bq, Qsplit, 0);
    ln_kernel<<<1024, 256, 0, stream>>>(conv_part, bsr, gamma, beta, xkv_);
    cq_kernel<<<512, 256, 0, stream>>>(xq, Wsr_, conv_part, Wq_, bq, Qsplit, 512);
  }
  kvproj_kernel<<<64, 256, 0, stream>>>(xkv_, Wkv_, bkv, Kq, Vt);
  attn_kernel<<<dim3(32, 8, 4), 256, 0, stream>>>(Qsplit, Kq, Vt, attno_);
  gemm_out_kernel<<<512, 256, 0, stream>>>(attno_, Wp_, bp, outp);
}

// Round 12
// 162.716 us; speedup vs baseline: 1.1422x; 1.0587x over previous
//
#include <hip/hip_runtime.h>

// B=4, H=W=64, N=4096, C=512, HEAD=8, dh=64, SR=4, Nk=256
// Split-bf16: val = hi + lo (both bf16).
// TERMS=3: aH*bH + aL*bH + aH*bL (drops only lo*lo ~4e-6 rel) — kv-proj.
// TERMS=2: aH*bH + aL*bH (drops weight-lo term) — conv, q-proj, out-proj.
//   Error budget: conv-2term -> x_kv err ~1e-3 -> K/V err ~5e-4 -> out ~2-3e-4;
//   measured absmax floor 2.44e-4, threshold 1.26e-3.

typedef __bf16 bf16x8 __attribute__((ext_vector_type(8)));
typedef float f32x4 __attribute__((ext_vector_type(4)));

__device__ __forceinline__ ushort f2bf(float v) {
  uint u = __float_as_uint(v);
  return (ushort)((u + 0x7FFFu + ((u >> 16) & 1u)) >> 16);
}
__device__ __forceinline__ float bf2f(ushort h) {
  return __uint_as_float((uint)h << 16);
}
__device__ __forceinline__ void gload16(const void* g, void* l) {
  __builtin_amdgcn_global_load_lds(
      (const __attribute__((address_space(1))) void*)g,
      (__attribute__((address_space(3))) void*)l, 16, 0, 0);
}
// bijective XCD swizzle for nwg % 8 == 0
__device__ __forceinline__ int xcd_swz(int bid, int nwg) {
  int cpx = nwg >> 3;
  return (bid & 7) * cpx + (bid >> 3);
}

// ---------------- fused prep: convert x, W's, Wsr, biases ----------------
__global__ __launch_bounds__(256) void prep_kernel(
    const float* __restrict__ x, const float* __restrict__ Wq,
    const float* __restrict__ Wp, const float* __restrict__ Wk,
    const float* __restrict__ Wv, const float* __restrict__ Wsr,
    const float* __restrict__ bk, const float* __restrict__ bv,
    ushort* __restrict__ xq, ushort* __restrict__ Wq_,
    ushort* __restrict__ Wp_, ushort* __restrict__ Wkv_,
    ushort* __restrict__ Wsr_, float* __restrict__ bkv) {
  __shared__ float t[32][33];
  int bid = blockIdx.x, tid = threadIdx.x;
  if (bid < 4096 + 512) {
    const float* src;
    ushort* dst;
    int gid;
    if (bid < 4096) {
      src = x; dst = xq; gid = bid * 256 + tid;
    } else {
      int z = (bid - 4096) >> 7;
      src = (z == 0) ? Wq : (z == 1) ? Wp : (z == 2) ? Wk : Wv;
      dst = (z == 0) ? Wq_ : (z == 1) ? Wp_ : (z == 2) ? Wkv_ : (Wkv_ + 512 * 1024);
      gid = ((bid - 4096) & 127) * 256 + tid;
    }
    int row = gid >> 6, c8 = (gid & 63) << 3;
    float4 a = *(const float4*)(src + (size_t)row * 512 + c8);
    float4 b = *(const float4*)(src + (size_t)row * 512 + c8 + 4);
    ushort h[8], l[8];
    float vv[8] = {a.x, a.y, a.z, a.w, b.x, b.y, b.z, b.w};
#pragma unroll
    for (int e = 0; e < 8; ++e) { h[e] = f2bf(vv[e]); l[e] = f2bf(vv[e] - bf2f(h[e])); }
    uint4 hp, lp;
    hp.x = h[0] | ((uint)h[1] << 16); hp.y = h[2] | ((uint)h[3] << 16);
    hp.z = h[4] | ((uint)h[5] << 16); hp.w = h[6] | ((uint)h[7] << 16);
    lp.x = l[0] | ((uint)l[1] << 16); lp.y = l[2] | ((uint)l[3] << 16);
    lp.z = l[4] | ((uint)l[5] << 16); lp.w = l[6] | ((uint)l[7] << 16);
    *(uint4*)(dst + (size_t)row * 1024 + c8) = hp;
    *(uint4*)(dst + (size_t)row * 1024 + 512 + c8) = lp;
  } else if (bid < 4096 + 512 + 4096) {
    int tb = bid - 4608;
    int z = tb >> 8, rem = tb & 255;
    int ci0 = (rem >> 4) << 5, co0 = (rem & 15) << 5;
    int tx = tid & 31, ty = tid >> 5;
#pragma unroll
    for (int i = 0; i < 32; i += 8)
      t[ty + i][tx] = Wsr[((size_t)z * 512 + ci0 + ty + i) * 512 + co0 + tx];
    __syncthreads();
#pragma unroll
    for (int i = 0; i < 32; i += 8) {
      float v = t[tx][ty + i];
      int co = co0 + ty + i, ci = ci0 + tx;
      ushort h = f2bf(v), l = f2bf(v - bf2f(h));
      Wsr_[((size_t)z * 512 + co) * 1024 + ci] = h;
      Wsr_[((size_t)z * 512 + co) * 1024 + 512 + ci] = l;
    }
  } else {
    bkv[tid] = bk[tid]; bkv[tid + 256] = bk[tid + 256];
    bkv[tid + 512] = bv[tid]; bkv[tid + 768] = bv[tid + 256];
  }
}

// ---------------- MFMA GEMM body: double-buffered 2-phase K-loop ----------------
// TERMS=3 -> 24 K-steps (logical K'=1536); TERMS=2 -> 16 K-steps (K'=1024).
// Section maps (identical formulas serve both):
//   ap = kk - (kk>=1024?1024:0)  -> A: hi, lo, [hi]
//   bp = kk - (kk>=512?512:0)    -> B: hi, hi, [lo]
// EPI=0: C fp32 + bias. EPI=1: Qsplit layout (LDS-coalesced). EPI=2: Kq/Vt scatter.
template <int EPI, int TERMS>
__device__ __forceinline__ void gemm_body(
    const ushort* __restrict__ A, const ushort* __restrict__ Bw,
    const float* __restrict__ bias, float* __restrict__ C,
    ushort* __restrict__ Qs, ushort* __restrict__ Kq, ushort* __restrict__ Vt,
    int N, int bx, int by, ushort* lds) {
  constexpr int NS = TERMS * 8;  // K-steps
  int tid = threadIdx.x;
  int lane = tid & 63, w = tid >> 6;
  int wr = w >> 1, wc = w & 1;
  int l15 = lane & 15, g = lane >> 4;
  int srow = lane >> 3;
  int scol = (lane & 7) ^ srow;

  const ushort* aBase = A + (size_t)(by * 128 + w * 32 + srow) * 1024 + scol * 8;
  const ushort* bBase = Bw + (size_t)(bx * 128 + w * 32 + srow) * 1024 + scol * 8;

  f32x4 acc[4][4];
#pragma unroll
  for (int i = 0; i < 4; ++i)
#pragma unroll
    for (int j = 0; j < 4; ++j) acc[i][j] = (f32x4){0.f, 0.f, 0.f, 0.f};

#define STAGE_G(ks, buf)                                              \
  {                                                                   \
    int kk = (ks) * 64;                                               \
    int ap = kk - (kk >= 1024 ? 1024 : 0);                            \
    int bp = kk - (kk >= 512 ? 512 : 0);                              \
    ushort* aD = lds + (buf) * 16384 + w * 2048;                      \
    ushort* bD = lds + (buf) * 16384 + 8192 + w * 2048;               \
    _Pragma("unroll") for (int t = 0; t < 4; ++t) {                   \
      gload16(aBase + (size_t)t * 8192 + ap, aD + t * 512);           \
      gload16(bBase + (size_t)t * 8192 + bp, bD + t * 512);           \
    }                                                                 \
  }

#define COMPUTE_G(buf)                                                         \
  {                                                                            \
    const ushort* As = lds + (buf) * 16384;                                    \
    const ushort* Bs = As + 8192;                                              \
    _Pragma("unroll") for (int kk2 = 0; kk2 < 2; ++kk2) {                      \
      int rb = kk2 * 4 + g;                                                    \
      bf16x8 af[4], bg[4];                                                     \
      _Pragma("unroll") for (int i = 0; i < 4; ++i) {                          \
        int row = wr * 64 + i * 16 + l15;                                      \
        af[i] = *(const bf16x8*)&As[row * 64 + ((rb ^ (row & 7)) << 3)];       \
      }                                                                        \
      _Pragma("unroll") for (int j = 0; j < 4; ++j) {                          \
        int col = wc * 64 + j * 16 + l15;                                      \
        bg[j] = *(const bf16x8*)&Bs[col * 64 + ((rb ^ (col & 7)) << 3)];       \
      }                                                                        \
      _Pragma("unroll") for (int i = 0; i < 4; ++i)                            \
        _Pragma("unroll") for (int j = 0; j < 4; ++j)                          \
          acc[i][j] =                                                          \
              __builtin_amdgcn_mfma_f32_16x16x32_bf16(af[i], bg[j], acc[i][j], \
                                                      0, 0, 0);                \
    }                                                                          \
  }

  STAGE_G(0, 0);
  __syncthreads();
  for (int ks = 0; ks < NS - 1; ++ks) {
    STAGE_G(ks + 1, (ks + 1) & 1);
    COMPUTE_G(ks & 1);
    __syncthreads();
  }
  COMPUTE_G((NS - 1) & 1);

#undef STAGE_G
#undef COMPUTE_G

  if (EPI == 0) {
#pragma unroll
    for (int j = 0; j < 4; ++j) {
      int col = bx * 128 + wc * 64 + j * 16 + l15;
      float bj = bias ? bias[col] : 0.f;
#pragma unroll
      for (int i = 0; i < 4; ++i) {
        int row0 = by * 128 + wr * 64 + i * 16 + g * 4;
#pragma unroll
        for (int r = 0; r < 4; ++r)
          C[(size_t)(row0 + r) * N + col] = acc[i][j][r] + bj;
      }
    }
  } else if (EPI == 1) {
    __syncthreads();
#pragma unroll
    for (int j = 0; j < 4; ++j) {
      int cl = wc * 64 + j * 16 + l15;
      float bj = bias[bx * 128 + cl];
#pragma unroll
      for (int i = 0; i < 4; ++i) {
        int rl0 = wr * 64 + i * 16 + g * 4;
#pragma unroll
        for (int r = 0; r < 4; ++r) {
          float v = (acc[i][j][r] + bj) * 0.125f;
          ushort h = f2bf(v), lo = f2bf(v - bf2f(h));
          lds[(rl0 + r) * 128 + cl] = h;
          lds[16384 + (rl0 + r) * 128 + cl] = lo;
        }
      }
    }
    __syncthreads();
#pragma unroll
    for (int it = 0; it < 8; ++it) {
      int c = tid + it * 256;
      int r = c >> 4, ck = c & 15;
      int grow = by * 128 + r;
      size_t base = ((size_t)grow * 8 + bx * 2 + (ck >> 3)) * 128 + (ck & 7) * 8;
      *(uint4*)(Qs + base) = *(const uint4*)&lds[r * 128 + ck * 8];
      *(uint4*)(Qs + base + 64) = *(const uint4*)&lds[16384 + r * 128 + ck * 8];
    }
  } else {
    // EPI=2: kv epilogue — scatter split-bf16 directly into Kq / Vt layouts.
#pragma unroll
    for (int j = 0; j < 4; ++j) {
      int col = bx * 128 + wc * 64 + j * 16 + l15;
      float bj = bias[col];
      bool isK = col < 512;
      int cp = isK ? col : col - 512;
      int hh = cp >> 6, d = cp & 63;
#pragma unroll
      for (int i = 0; i < 4; ++i) {
        int row0 = by * 128 + wr * 64 + i * 16 + g * 4;
#pragma unroll
        for (int r = 0; r < 4; ++r) {
          int row = row0 + r;
          int b = row >> 8, kk = row & 255;
          float v = acc[i][j][r] + bj;
          ushort h = f2bf(v), lo = f2bf(v - bf2f(h));
          if (isK) {
            size_t base = ((size_t)((b * 8 + hh) * 256) + kk) * 128 + d;
            Kq[base] = h; Kq[base + 64] = lo;
          } else {
            size_t base = ((size_t)((b * 8 + hh) * 64) + d) * 512 + kk;
            Vt[base] = h; Vt[base + 256] = lo;
          }
        }
      }
    }
  }
}

// ---------------- conv body (split-16, one tap per z; TERMS templated) ----------------
template <int TERMS>
__device__ __forceinline__ void conv_body(
    const ushort* __restrict__ xq, const ushort* __restrict__ Wsr_,
    float* __restrict__ part, int bx, int by, int z, ushort* lds) {
  constexpr int NS = TERMS * 8;
  int kh = z >> 2, kw = z & 3;
  int tid = threadIdx.x;
  int lane = tid & 63, w = tid >> 6;
  int wr = w >> 1, wc = w & 1;
  int l15 = lane & 15, g = lane >> 4;
  int srow = lane >> 3;
  int scol = (lane & 7) ^ srow;

  const ushort* aBase[4];
#pragma unroll
  for (int t = 0; t < 4; ++t) {
    int gm = by * 128 + w * 32 + t * 8 + srow;
    int xr = (gm >> 8) * 4096 + ((((gm >> 4) & 15) << 2) + kh) * 64 +
             ((gm & 15) << 2) + kw;
    aBase[t] = xq + (size_t)xr * 1024 + scol * 8;
  }
  const ushort* bBase =
      Wsr_ + ((size_t)z * 512 + bx * 128 + w * 32 + srow) * 1024 + scol * 8;

  f32x4 acc[4][4];
#pragma unroll
  for (int i = 0; i < 4; ++i)
#pragma unroll
    for (int j = 0; j < 4; ++j) acc[i][j] = (f32x4){0.f, 0.f, 0.f, 0.f};

#define STAGE_C(ks, buf)                                              \
  {                                                                   \
    int kk = (ks) * 64;                                               \
    int ap = kk - (kk >= 1024 ? 1024 : 0);                            \
    int bp = kk - (kk >= 512 ? 512 : 0);                              \
    ushort* aD = lds + (buf) * 16384 + w * 2048;                      \
    ushort* bD = lds + (buf) * 16384 + 8192 + w * 2048;               \
    _Pragma("unroll") for (int t = 0; t < 4; ++t) {                   \
      gload16(aBase[t] + ap, aD + t * 512);                           \
      gload16(bBase + (size_t)t * 8192 + bp, bD + t * 512);           \
    }                                                                 \
  }

#define COMPUTE_C(buf)                                                         \
  {                                                                            \
    const ushort* As = lds + (buf) * 16384;                                    \
    const ushort* Bs = As + 8192;                                              \
    _Pragma("unroll") for (int kk2 = 0; kk2 < 2; ++kk2) {                      \
      int rb = kk2 * 4 + g;                                                    \
      bf16x8 af[4], bg[4];                                                     \
      _Pragma("unroll") for (int i = 0; i < 4; ++i) {                          \
        int row = wr * 64 + i * 16 + l15;                                      \
        af[i] = *(const bf16x8*)&As[row * 64 + ((rb ^ (row & 7)) << 3)];       \
      }                                                                        \
      _Pragma("unroll") for (int j = 0; j < 4; ++j) {                          \
        int col = wc * 64 + j * 16 + l15;                                      \
        bg[j] = *(const bf16x8*)&Bs[col * 64 + ((rb ^ (col & 7)) << 3)];       \
      }                                                                        \
      _Pragma("unroll") for (int i = 0; i < 4; ++i)                            \
        _Pragma("unroll") for (int j = 0; j < 4; ++j)                          \
          acc[i][j] =                                                          \
              __builtin_amdgcn_mfma_f32_16x16x32_bf16(af[i], bg[j], acc[i][j], \
                                                      0, 0, 0);                \
    }                                                                          \
  }

  STAGE_C(0, 0);
  __syncthreads();
  for (int ks = 0; ks < NS - 1; ++ks) {
    STAGE_C(ks + 1, (ks + 1) & 1);
    COMPUTE_C(ks & 1);
    __syncthreads();
  }
  COMPUTE_C((NS - 1) & 1);

#undef STAGE_C
#undef COMPUTE_C

  float* Cp = part + (size_t)z * 524288;
#pragma unroll
  for (int j = 0; j < 4; ++j) {
    int col = bx * 128 + wc * 64 + j * 16 + l15;
#pragma unroll
    for (int i = 0; i < 4; ++i) {
      int row0 = by * 128 + wr * 64 + i * 16 + g * 4;
#pragma unroll
      for (int r = 0; r < 4; ++r)
        Cp[(size_t)(row0 + r) * 512 + col] = acc[i][j][r];
    }
  }
}

// conv (work-ids 0..511, TERMS=2) + q-proj (512..1023, TERMS=2) — uniform 16 steps
__global__ __launch_bounds__(256) void cq_kernel(
    const ushort* __restrict__ xq, const ushort* __restrict__ Wsr_,
    float* __restrict__ part, const ushort* __restrict__ Wq_,
    const float* __restrict__ bq, ushort* __restrict__ Qs, int base) {
  __shared__ __align__(16) ushort lds[32768];
  int bid = xcd_swz(blockIdx.x, gridDim.x) + base;
  if (bid < 512) {
    conv_body<2>(xq, Wsr_, part, bid & 3, (bid >> 2) & 7, bid >> 5, lds);
  } else {
    int b2 = bid - 512;
    gemm_body<1, 2>(xq, Wq_, bq, nullptr, Qs, nullptr, nullptr, 512,
                    b2 & 3, b2 >> 2, lds);
  }
}

// kv-proj: 64 blocks, writes Kq/Vt directly (EPI=2, TERMS=3 — K/V precision matters)
__global__ __launch_bounds__(256) void kvproj_kernel(
    const ushort* __restrict__ xkv_, const ushort* __restrict__ Wkv_,
    const float* __restrict__ bkv, ushort* __restrict__ Kq,
    ushort* __restrict__ Vt) {
  __shared__ __align__(16) ushort lds[32768];
  int bid = xcd_swz(blockIdx.x, 64);
  gemm_body<2, 3>(xkv_, Wkv_, bkv, nullptr, nullptr, Kq, Vt, 1024,
                  bid & 7, bid >> 3, lds);
}

// out-proj (TERMS=2)
__global__ __launch_bounds__(256) void gemm_out_kernel(
    const ushort* __restrict__ A, const ushort* __restrict__ Bw,
    const float* __restrict__ bias, float* __restrict__ C) {
  __shared__ __align__(16) ushort lds[32768];
  int bid = xcd_swz(blockIdx.x, 512);
  gemm_body<0, 2>(A, Bw, bias, C, nullptr, nullptr, nullptr, 512,
                  bid & 3, bid >> 2, lds);
}

// ---------------- partial-sum(16) + bias + LayerNorm -> split-bf16 ----------------
__global__ __launch_bounds__(256) void ln_kernel(
    const float* __restrict__ part, const float* __restrict__ bsr,
    const float* __restrict__ gamma, const float* __restrict__ beta,
    ushort* __restrict__ xkv_) {
  int row = blockIdx.x;
  int t = threadIdx.x;
  float v0 = bsr[t], v1 = bsr[t + 256];
  for (int p = 0; p < 16; ++p) {
    v0 += part[(size_t)p * 524288 + (size_t)row * 512 + t];
    v1 += part[(size_t)p * 524288 + (size_t)row * 512 + t + 256];
  }
  float s = v0 + v1, sq = v0 * v0 + v1 * v1;
#pragma unroll
  for (int o = 1; o < 64; o <<= 1) {
    s += __shfl_xor(s, o);
    sq += __shfl_xor(sq, o);
  }
  __shared__ float red[8];
  int wv = t >> 6;
  if ((t & 63) == 0) { red[wv] = s; red[4 + wv] = sq; }
  __syncthreads();
  s = red[0] + red[1] + red[2] + red[3];
  sq = red[4] + red[5] + red[6] + red[7];
  float mu = s * (1.0f / 512.0f);
  float var = sq * (1.0f / 512.0f) - mu * mu;
  float rs = rsqrtf(var + 1e-5f);
  float y0 = (v0 - mu) * rs * gamma[t] + beta[t];
  float y1 = (v1 - mu) * rs * gamma[t + 256] + beta[t + 256];
  ushort h0 = f2bf(y0), h1 = f2bf(y1);
  xkv_[(size_t)row * 1024 + t] = h0;
  xkv_[(size_t)row * 1024 + t + 256] = h1;
  xkv_[(size_t)row * 1024 + 512 + t] = f2bf(y0 - bf2f(h0));
  xkv_[(size_t)row * 1024 + 512 + t + 256] = f2bf(y1 - bf2f(h1));
}

// ---------------- MFMA flash attention: 128 q/block, DMA staging, dbuf ----------------
__global__ __launch_bounds__(256, 2) void attn_kernel(
    const ushort* __restrict__ Qs, const ushort* __restrict__ Kq,
    const ushort* __restrict__ Vt, ushort* __restrict__ attno) {
  __shared__ __align__(16) char arena[81920];
  ushort* KsL = (ushort*)arena;
  ushort* VtL = (ushort*)(arena + 32768);
  ushort* PL = (ushort*)(arena + 65536);
  float* ob = (float*)arena;

  int tid = threadIdx.x;
  int qb = blockIdx.x, h = blockIdx.y, b = blockIdx.z;
  int n0 = qb * 128, bh = b * 8 + h;
  int lane = tid & 63, w = tid >> 6;
  int q15 = lane & 15, g = lane >> 4;

  const ushort* kbase = Kq + (size_t)bh * 256 * 128;
  const ushort* vbase = Vt + (size_t)bh * 64 * 512;

  bf16x8 qf[2][2][2];
#pragma unroll
  for (int set = 0; set < 2; ++set) {
    const ushort* qptr =
        Qs + ((size_t)(b * 4096 + n0 + set * 64 + w * 16 + q15) * 8 + h) * 128;
#pragma unroll
    for (int s = 0; s < 2; ++s)
#pragma unroll
      for (int kb = 0; kb < 2; ++kb)
        qf[set][s][kb] = *(const bf16x8*)(qptr + s * 64 + kb * 32 + g * 8);
  }

  f32x4 accO[2][4];
#pragma unroll
  for (int set = 0; set < 2; ++set)
#pragma unroll
    for (int t = 0; t < 4; ++t) accO[set][t] = (f32x4){0.f, 0.f, 0.f, 0.f};
  float m[2] = {-1e30f, -1e30f}, l[2] = {0.f, 0.f};

#define STAGE_A(cc, buf)                                                     \
  {                                                                          \
    _Pragma("unroll") for (int i = 0; i < 4; ++i) {                          \
      int rb_ = w * 16 + i * 4;                                              \
      int r_ = rb_ + (lane >> 4);                                            \
      int sb_ = (lane & 15) ^ (r_ & 7);                                      \
      gload16(kbase + (size_t)((cc) * 64 + r_) * 128 + (sb_ << 3),           \
              KsL + (buf) * 8192 + rb_ * 128);                               \
      gload16(vbase + (size_t)r_ * 512 + ((sb_ >> 3) << 8) + (cc) * 64 +     \
                  ((sb_ & 7) << 3),                                          \
              VtL + (buf) * 8192 + rb_ * 128);                               \
    }                                                                        \
  }

  STAGE_A(0, 0);
  __syncthreads();

  for (int c = 0; c < 4; ++c) {
    int buf = c & 1;
    if (c < 3) STAGE_A(c + 1, buf ^ 1);
    const ushort* Ks = KsL + buf * 8192;
    const ushort* Vs = VtL + buf * 8192;

    f32x4 accS[2][4];
#pragma unroll
    for (int set = 0; set < 2; ++set)
#pragma unroll
      for (int t = 0; t < 4; ++t) accS[set][t] = (f32x4){0.f, 0.f, 0.f, 0.f};
#pragma unroll
    for (int kb = 0; kb < 2; ++kb) {
      bf16x8 ak[4], al[4];
#pragma unroll
      for (int t = 0; t < 4; ++t) {
        int kkr = t * 16 + q15;
        ak[t] = *(const bf16x8*)&Ks[kkr * 128 + (((kb * 4 + g) ^ (kkr & 7)) << 3)];
        al[t] = *(const bf16x8*)&Ks[kkr * 128 + (((8 + kb * 4 + g) ^ (kkr & 7)) << 3)];
      }
#pragma unroll
      for (int set = 0; set < 2; ++set) {
#pragma unroll
        for (int t = 0; t < 4; ++t)
          accS[set][t] = __builtin_amdgcn_mfma_f32_16x16x32_bf16(
              ak[t], qf[set][0][kb], accS[set][t], 0, 0, 0);
#pragma unroll
        for (int t = 0; t < 4; ++t)
          accS[set][t] = __builtin_amdgcn_mfma_f32_16x16x32_bf16(
              ak[t], qf[set][1][kb], accS[set][t], 0, 0, 0);
#pragma unroll
        for (int t = 0; t < 4; ++t)
          accS[set][t] = __builtin_amdgcn_mfma_f32_16x16x32_bf16(
              al[t], qf[set][0][kb], accS[set][t], 0, 0, 0);
      }
    }

#pragma unroll
    for (int set = 0; set < 2; ++set) {
      int qrowL = set * 64 + w * 16 + q15;
      float mx = -1e30f;
#pragma unroll
      for (int t = 0; t < 4; ++t)
#pragma unroll
        for (int r = 0; r < 4; ++r) mx = fmaxf(mx, accS[set][t][r]);
      mx = fmaxf(mx, __shfl_xor(mx, 16));
      mx = fmaxf(mx, __shfl_xor(mx, 32));
      float mn = fmaxf(m[set], mx);
      float fac = __expf(m[set] - mn);
      m[set] = mn;
      float sum = 0.f;
      ushort ph[4][4];
#pragma unroll
      for (int t = 0; t < 4; ++t)
#pragma unroll
        for (int r = 0; r < 4; ++r) {
          float p = __expf(accS[set][t][r] - mn);
          ushort hp = f2bf(p);
          ph[t][r] = hp;
          sum += bf2f(hp);
        }
      sum += __shfl_xor(sum, 16);
      sum += __shfl_xor(sum, 32);
      l[set] = l[set] * fac + sum;
#pragma unroll
      for (int t = 0; t < 4; ++t) {
        accO[set][t][0] *= fac; accO[set][t][1] *= fac;
        accO[set][t][2] *= fac; accO[set][t][3] *= fac;
      }
#pragma unroll
      for (int t = 0; t < 4; ++t)
#pragma unroll
        for (int rp = 0; rp < 4; rp += 2) {
          uint u = ph[t][rp] | ((uint)ph[t][rp + 1] << 16);
          int kkl = t * 16 + g * 4 + rp;
          int blk = kkl >> 3, off = kkl & 7;
          *(uint*)((char*)PL + qrowL * 128 + ((blk ^ (q15 & 7)) << 4) + off * 2) = u;
        }
    }
    __syncthreads();

    bf16x8 pf[2][2];
#pragma unroll
    for (int set = 0; set < 2; ++set) {
      int qrowL = set * 64 + w * 16 + q15;
#pragma unroll
      for (int kb = 0; kb < 2; ++kb)
        pf[set][kb] = *(const bf16x8*)((char*)PL + qrowL * 128 +
                                       (((kb * 4 + g) ^ (q15 & 7)) << 4));
    }
#pragma unroll
    for (int s = 0; s < 2; ++s)
#pragma unroll
      for (int kb = 0; kb < 2; ++kb)
#pragma unroll
        for (int t = 0; t < 4; ++t) {
          int d = t * 16 + q15;
          bf16x8 vf =
              *(const bf16x8*)&Vs[d * 128 + (((s * 8 + kb * 4 + g) ^ (d & 7)) << 3)];
          accO[0][t] = __builtin_amdgcn_mfma_f32_16x16x32_bf16(vf, pf[0][kb],
                                                               accO[0][t], 0, 0, 0);
          accO[1][t] = __builtin_amdgcn_mfma_f32_16x16x32_bf16(vf, pf[1][kb],
                                                               accO[1][t], 0, 0, 0);
        }
    __syncthreads();
  }
#undef STAGE_A

#pragma unroll
  for (int set = 0; set < 2; ++set) {
    if (set) __syncthreads();
    float inv = 1.0f / l[set];
#pragma unroll
    for (int t = 0; t < 4; ++t)
#pragma unroll
      for (int r = 0; r < 4; ++r)
        ob[(t * 16 + g * 4 + r) * 68 + w * 16 + q15] = accO[set][t][r] * inv;
    __syncthreads();
#pragma unroll
    for (int i = 0; i < 2; ++i) {
      int idx = tid + i * 256;
      int qq = idx >> 3, d8 = (idx & 7) << 3;
      ushort hh[8], ll[8];
#pragma unroll
      for (int jj = 0; jj < 8; ++jj) {
        float v = ob[(d8 + jj) * 68 + qq];
        hh[jj] = f2bf(v);
        ll[jj] = f2bf(v - bf2f(hh[jj]));
      }
      uint4 hp, lp;
      hp.x = hh[0] | ((uint)hh[1] << 16); hp.y = hh[2] | ((uint)hh[3] << 16);
      hp.z = hh[4] | ((uint)hh[5] << 16); hp.w = hh[6] | ((uint)hh[7] << 16);
      lp.x = ll[0] | ((uint)ll[1] << 16); lp.y = ll[2] | ((uint)ll[3] << 16);
      lp.z = ll[4] | ((uint)ll[5] << 16); lp.w = ll[6] | ((uint)ll[7] << 16);
      size_t rowb = (size_t)(b * 4096 + n0 + set * 64 + qq) * 1024 + h * 64 + d8;
      *(uint4*)(attno + rowb) = hp;
      *(uint4*)(attno + rowb + 512) = lp;
    }
  }
}

// ---------------- launch ----------------
extern "C" void kernel_launch(void* const* d_in, const int* in_sizes, int n_in,
                              void* d_out, int out_size, void* d_ws, size_t ws_size,
                              hipStream_t stream) {
  const float* x     = (const float*)d_in[0];
  const float* Wq    = (const float*)d_in[1];
  const float* bq    = (const float*)d_in[2];
  const float* Wk    = (const float*)d_in[3];
  const float* bk    = (const float*)d_in[4];
  const float* Wv    = (const float*)d_in[5];
  const float* bv    = (const float*)d_in[6];
  const float* Wp    = (const float*)d_in[7];
  const float* bp    = (const float*)d_in[8];
  const float* Wsr   = (const float*)d_in[9];
  const float* bsr   = (const float*)d_in[10];
  const float* gamma = (const float*)d_in[11];
  const float* beta  = (const float*)d_in[12];

  float* ws = (float*)d_ws;
  // Fused layout end = 31,982,592 floats = 127,930,368 bytes.
  bool bigws = ws_size >= 127930368ull;

  ushort* xq     = (ushort*)ws;                 // regionA; attno_ later
  ushort* attno_ = (ushort*)ws;
  float*  conv_part = ws + 8388608;             // [16][1024][512] f32
  ushort* Qsplit = bigws ? (ushort*)(ws + 16777216)
                         : (ushort*)(ws + 8388608);   // aliases conv_part (compact)
  size_t tail = bigws ? 25165824 : 16777216;
  ushort* Wsr_ = (ushort*)(ws + tail);          // 8,388,608 us = 4,194,304 fl
  float*  rest = ws + tail + 4194304;
  ushort* Wq_  = (ushort*)rest;                 // 524,288 us = 262,144 fl
  ushort* Wp_  = (ushort*)(rest + 262144);      // 524,288 us = 262,144 fl
  ushort* Wkv_ = (ushort*)(rest + 524288);      // 1,048,576 us = 524,288 fl
  ushort* xkv_ = (ushort*)(rest + 1048576);     // 1,048,576 us = 524,288 fl
  ushort* Kq   = (ushort*)(rest + 1572864);     // 1,048,576 us = 524,288 fl
  ushort* Vt   = (ushort*)(rest + 2097152);     // 1,048,576 us = 524,288 fl
  float*  bkv  = rest + 2621440;                // 1,024 fl
  float* outp = (float*)d_out;

  prep_kernel<<<8705, 256, 0, stream>>>(x, Wq, Wp, Wk, Wv, Wsr, bk, bv,
                                        xq, Wq_, Wp_, Wkv_, Wsr_, bkv);
  if (bigws) {
    cq_kernel<<<1024, 256, 0, stream>>>(xq, Wsr_, conv_part, Wq_, bq, Qsplit, 0);
    ln_kernel<<<1024, 256, 0, stream>>>(conv_part, bsr, gamma, beta, xkv_);
  } else {
    cq_kernel<<<512, 256, 0, stream>>>(xq, Wsr_, conv_part, Wq_, bq, Qsplit, 0);
    ln_kernel<<<1024, 256, 0, stream>>>(conv_part, bsr, gamma, beta, xkv_);
    cq_kernel<<<512, 256, 0, stream>>>(xq, Wsr_, conv_part, Wq_, bq, Qsplit, 512);
  }
  kvproj_kernel<<<64, 256, 0, stream>>>(xkv_, Wkv_, bkv, Kq, Vt);
  attn_kernel<<<dim3(32, 8, 4), 256, 0, stream>>>(Qsplit, Kq, Vt, attno_);
  gemm_out_kernel<<<512, 256, 0, stream>>>(attno_, Wp_, bp, outp);
}